// Round 7
// baseline (502.447 us; speedup 1.0000x reference)
//
#include <hip/hip_runtime.h>
#include <math.h>

typedef _Float16 half8 __attribute__((ext_vector_type(8)));
typedef float    f32x4 __attribute__((ext_vector_type(4)));

#define NROWS 16384
#define DIMS  512
#define KC    8192
#define DELTA 0.5f
#define CAP   262144

// sortable-key helpers: smaller float -> smaller unsigned
__device__ inline unsigned fkey(float v) {
    unsigned u = __float_as_uint(v);
    return (u & 0x80000000u) ? ~u : (u | 0x80000000u);
}
__device__ inline float unfkey(unsigned u) {
    return (u & 0x80000000u) ? __uint_as_float(u & 0x7FFFFFFFu)
                             : __uint_as_float(~u);
}
__device__ inline unsigned long long shflxor_u64(unsigned long long v, int m) {
    int lo = __shfl_xor((int)(unsigned)(v & 0xffffffffull), m, 64);
    int hi = __shfl_xor((int)(unsigned)(v >> 32), m, 64);
    return ((unsigned long long)(unsigned)hi << 32) | (unsigned)lo;
}

// ---------------------------------------------------------------------------
// K0: fused prep. blocks [0,1024): cvt z panels; [1024,1536): cvt emb panels;
// [1536,3584): emb row sum-of-squares (fp64 accum); block 0 also zeroes ncand.
// cvt packed layout (halfs): p*131072 + s*8192 + c*8 where chunk unit
// c = f*64 + lg*16 + rr  (f = 16-row fragment, lg = 8-half k-group, rr = row).
// A 1KB fragment chunk read at +lane*16 gives lane -> (lg=lane>>4, rr=lane&15).
// ---------------------------------------------------------------------------
__global__ __launch_bounds__(256)
void prep_kernel(const float* __restrict__ z, const float* __restrict__ emb,
                 _Float16* __restrict__ zh16, _Float16* __restrict__ eh16,
                 float* __restrict__ esf, int* __restrict__ ncand)
{
    int b = blockIdx.x, t = threadIdx.x;
    if (b == 0 && t == 0) *ncand = 0;
    if (b < 1536) {
        const float* src;
        _Float16* dst;
        int pb;
        if (b < 1024) { src = z;   dst = zh16; pb = b; }
        else          { src = emb; dst = eh16; pb = b - 1024; }
        int p = pb >> 4, s = pb & 15;
        _Float16* dbase = dst + (size_t)p * 131072 + s * 8192;
        #pragma unroll
        for (int q = 0; q < 4; ++q) {
            int c = q * 256 + t;
            int f = c >> 6, lg = (c >> 4) & 3, rr = c & 15;
            int row = p * 256 + f * 16 + rr;
            const float* sp = src + (size_t)row * DIMS + s * 32 + lg * 8;
            float4 v0 = *(const float4*)(sp + 0);
            float4 v1 = *(const float4*)(sp + 4);
            half8 h;
            h[0] = (_Float16)v0.x; h[1] = (_Float16)v0.y;
            h[2] = (_Float16)v0.z; h[3] = (_Float16)v0.w;
            h[4] = (_Float16)v1.x; h[5] = (_Float16)v1.y;
            h[6] = (_Float16)v1.z; h[7] = (_Float16)v1.w;
            *(half8*)(dbase + c * 8) = h;
        }
    } else {
        int b2 = b - 1536;
        int w = b2 * 4 + (t >> 6);          // emb row 0..8191
        int lane = t & 63;
        const float* r = emb + (size_t)w * DIMS;
        float4 v0 = *(const float4*)(r + lane * 4);
        float4 v1 = *(const float4*)(r + 256 + lane * 4);
        double s = (double)v0.x * v0.x + (double)v0.y * v0.y +
                   (double)v0.z * v0.z + (double)v0.w * v0.w +
                   (double)v1.x * v1.x + (double)v1.y * v1.y +
                   (double)v1.z * v1.z + (double)v1.w * v1.w;
        #pragma unroll
        for (int off = 32; off; off >>= 1) s += __shfl_down(s, off);
        if (lane == 0) esf[w] = (float)s;
    }
}

// ---------------------------------------------------------------------------
// K1: fp16 screen GEMM + per-(row, 256-col-block) top-2 table.
// R7 structure: 256x256 block, FOUR waves (2Mx2N), wave tile 128x128
// (i8 x j8 -> 0.25 ds_reads per MFMA; acc = 256 AGPRs via unified file;
// 1 wave/SIMD, matrix pipe saturated by a single wave's 64 independent
// MFMAs). 3 LDS buffers (96KB), depth-2 prefetch via global_load_lds,
// counted vmcnt (16/8/0), raw s_barrier only (no vmcnt(0) drain per step).
// Fragment reads are lane-linear (chunk + lane*16): conflict-free.
// Safety: stage at step s targets buf[(s+2)%3] == buf[(s-1)%3], whose last
// readers finished before the step-s barrier; stage->read distance is
// ~2 steps (>1500 cyc) >> worst-case load latency; per-wave vmcnt(16)
// forces step-s chunks landed while allowing 16 newer in flight.
// ---------------------------------------------------------------------------
__global__ __launch_bounds__(256, 1)
void screen_kernel(const char* __restrict__ zh, const char* __restrict__ eh,
                   const float* __restrict__ esf,
                   unsigned long long* __restrict__ tab)
{
    __shared__ char smem[98304];   // 3 x (A 16K | B 16K)

    const int t    = threadIdx.x;
    const int lane = t & 63;
    const int wave = t >> 6;
    const int lg   = lane >> 4;
    const int lr   = lane & 15;
    const int wm   = wave >> 1;      // 0..1 (row half: 128 rows)
    const int wn   = wave & 1;       // 0..1 (col half: 128 cols)
    const int bx   = blockIdx.x;     // row panel 0..63
    const int by   = blockIdx.y;     // col panel 0..31

    const char* gA = zh + (size_t)bx * 262144;
    const char* gB = eh + (size_t)by * 262144;

    f32x4 acc[8][8];
    #pragma unroll
    for (int i = 0; i < 8; ++i)
        #pragma unroll
        for (int j = 0; j < 8; ++j)
            acc[i][j] = (f32x4){0.f, 0.f, 0.f, 0.f};

    typedef const __attribute__((address_space(1))) unsigned int gq_t;
    typedef __attribute__((address_space(3))) unsigned int lq_t;
    // stage K-step s (A 16KB + B 16KB) into dstbuf: 8 gloads/thread.
    // dst is wave-uniform (wave*64*16 chunk base); src carries +lane*16.
    #define STAGE(dstbuf, s)                                                  \
    {                                                                         \
        const char* gsA = gA + (size_t)(s) * 16384;                           \
        const char* gsB = gB + (size_t)(s) * 16384;                           \
        _Pragma("unroll")                                                     \
        for (int q = 0; q < 4; ++q) {                                         \
            int cb = (q * 256 + wave * 64) * 16;                              \
            __builtin_amdgcn_global_load_lds(                                 \
                (gq_t*)(gsA + cb + lane * 16), (lq_t*)((dstbuf) + cb),        \
                16, 0, 0);                                                    \
            __builtin_amdgcn_global_load_lds(                                 \
                (gq_t*)(gsB + cb + lane * 16),                                \
                (lq_t*)((dstbuf) + 16384 + cb), 16, 0, 0);                    \
        }                                                                     \
    }

    char* p0 = smem;
    char* p1 = smem + 32768;
    char* p2 = smem + 65536;
    STAGE(p0, 0);
    STAGE(p1, 1);

    #pragma unroll 1
    for (int s = 0; s < 16; ++s) {
        __builtin_amdgcn_s_barrier();          // ends step s-1 reads
        if (s < 14) STAGE(p2, s + 2);          // into buf last read at s-1
        if (s <= 13)      asm volatile("s_waitcnt vmcnt(16)" ::: "memory");
        else if (s == 14) asm volatile("s_waitcnt vmcnt(8)"  ::: "memory");
        else              asm volatile("s_waitcnt vmcnt(0)"  ::: "memory");

        const char* Ab = p0 + wm * 8192 + lane * 16;
        const char* Bb = p0 + 16384 + wn * 8192 + lane * 16;
        half8 af[8], bf[8];
        #pragma unroll
        for (int i = 0; i < 8; ++i) af[i] = *(const half8*)(Ab + i * 1024);
        #pragma unroll
        for (int j = 0; j < 8; ++j) bf[j] = *(const half8*)(Bb + j * 1024);

        #pragma unroll
        for (int i = 0; i < 8; ++i)
            #pragma unroll
            for (int j = 0; j < 8; ++j)
                acc[i][j] = __builtin_amdgcn_mfma_f32_16x16x32_f16(
                    af[i], bf[j], acc[i][j], 0, 0, 0);

        char* tmp = p0; p0 = p1; p1 = p2; p2 = tmp;
    }

    // ---- epilogue: per-row top-2 within this block's 256 cols ----
    __syncthreads();
    unsigned long long* mb = (unsigned long long*)smem;  // [256][2 wn][2] 8KB
    float es_j[8];
    #pragma unroll
    for (int j = 0; j < 8; ++j)
        es_j[j] = esf[by * 256 + wn * 128 + j * 16 + lr];

    #pragma unroll
    for (int i = 0; i < 8; ++i) {
        #pragma unroll
        for (int r = 0; r < 4; ++r) {
            unsigned long long k1 = ~0ull, k2 = ~0ull;
            #pragma unroll
            for (int j = 0; j < 8; ++j) {
                float v = fmaf(-2.f, acc[i][j][r], es_j[j]);
                int col = by * 256 + wn * 128 + j * 16 + lr;
                unsigned long long k =
                    ((unsigned long long)fkey(v) << 32) | (unsigned)col;
                if (k < k1) { k2 = k1; k1 = k; }
                else if (k < k2) { k2 = k; }
            }
            #pragma unroll
            for (int m = 1; m <= 8; m <<= 1) {
                unsigned long long o1 = shflxor_u64(k1, m);
                unsigned long long o2 = shflxor_u64(k2, m);
                unsigned long long n1 = k1 < o1 ? k1 : o1;
                unsigned long long hi = k1 < o1 ? o1 : k1;
                unsigned long long l2 = k2 < o2 ? k2 : o2;
                k1 = n1;
                k2 = hi < l2 ? hi : l2;
            }
            if (lr == 0) {
                int row = wm * 128 + i * 16 + lg * 4 + r;
                mb[(row * 2 + wn) * 2 + 0] = k1;
                mb[(row * 2 + wn) * 2 + 1] = k2;
            }
        }
    }
    __syncthreads();

    if (t < 256) {
        unsigned long long a1 = mb[(t * 2 + 0) * 2 + 0];
        unsigned long long a2 = mb[(t * 2 + 0) * 2 + 1];
        unsigned long long b1 = mb[(t * 2 + 1) * 2 + 0];
        unsigned long long b2 = mb[(t * 2 + 1) * 2 + 1];
        unsigned long long k1 = a1 < b1 ? a1 : b1;
        unsigned long long hi = a1 < b1 ? b1 : a1;
        unsigned long long lo2 = a1 < b1 ? a2 : b2;
        unsigned long long k2 = hi < lo2 ? hi : lo2;
        size_t o = ((size_t)(bx * 256 + t) * 32 + by) * 2;
        tab[o + 0] = k1;
        tab[o + 1] = k2;
    }
}

// ---------------------------------------------------------------------------
// K2: collect candidates within DELTA of each row's approx min.
// Also inits rowkey and zeroes counts (replaces memsets).
// ---------------------------------------------------------------------------
__global__ __launch_bounds__(256)
void collect_kernel(const unsigned long long* __restrict__ tab,
                    unsigned* __restrict__ cand, int* __restrict__ ncand,
                    unsigned long long* __restrict__ rowkey,
                    int* __restrict__ counts)
{
    int t = threadIdx.x, lane = t & 63;
    if (blockIdx.x < 32) counts[blockIdx.x * 256 + t] = 0;
    int row = blockIdx.x * 4 + (t >> 6);
    unsigned long long k = tab[(size_t)row * 64 + lane];
    unsigned long long m = k;
    #pragma unroll
    for (int mask = 1; mask <= 32; mask <<= 1) {
        unsigned long long o = shflxor_u64(m, mask);
        m = o < m ? o : m;
    }
    if (lane == 0) rowkey[row] = ~0ull;
    float vb = unfkey((unsigned)(m >> 32));
    unsigned uthr = fkey(vb + DELTA);
    if ((unsigned)(k >> 32) <= uthr) {
        int pos = atomicAdd(ncand, 1);
        if (pos < CAP)
            cand[pos] = ((unsigned)row << 13) | (unsigned)(k & 8191u);
    }
}

// ---------------------------------------------------------------------------
// K3: exact fp32 rescore of candidates -> atomicMin final row keys.
// ---------------------------------------------------------------------------
__global__ __launch_bounds__(256)
void rescore_kernel(const float* __restrict__ z, const float* __restrict__ emb,
                    const float* __restrict__ esf,
                    const unsigned* __restrict__ cand,
                    const int* __restrict__ ncand,
                    unsigned long long* __restrict__ rowkey)
{
    int n = *ncand; if (n > CAP) n = CAP;
    int wid = blockIdx.x * 4 + (threadIdx.x >> 6);
    int lane = threadIdx.x & 63;
    for (int c = wid; c < n; c += 4096) {
        unsigned pc = cand[c];
        int row = pc >> 13, col = pc & 8191;
        const float4* zr = (const float4*)(z + (size_t)row * DIMS + lane * 8);
        const float4* er = (const float4*)(emb + (size_t)col * DIMS + lane * 8);
        float4 a0 = zr[0], a1 = zr[1], b0 = er[0], b1 = er[1];
        float s = a0.x * b0.x;
        s = fmaf(a0.y, b0.y, s); s = fmaf(a0.z, b0.z, s);
        s = fmaf(a0.w, b0.w, s); s = fmaf(a1.x, b1.x, s);
        s = fmaf(a1.y, b1.y, s); s = fmaf(a1.z, b1.z, s);
        s = fmaf(a1.w, b1.w, s);
        #pragma unroll
        for (int mask = 32; mask; mask >>= 1) s += __shfl_xor(s, mask);
        if (lane == 0) {
            float v = fmaf(-2.f, s, esf[col]);
            unsigned long long key =
                ((unsigned long long)fkey(v) << 32) | (unsigned)col;
            atomicMin(rowkey + row, key);
        }
    }
}

// ---------------------------------------------------------------------------
// K4: gather + loss partials + index output + histogram.
// ---------------------------------------------------------------------------
__global__ __launch_bounds__(256)
void gather_loss_kernel(const float* __restrict__ z, const float* __restrict__ emb,
                        const unsigned long long* __restrict__ rowkey,
                        float* __restrict__ outq, float* __restrict__ out_idx_f,
                        int* __restrict__ counts, float* __restrict__ bsums)
{
    int gid = blockIdx.x * 256 + threadIdx.x;
    int row = gid >> 7;
    int c4  = (gid & 127) << 2;
    int idx = (int)(rowkey[row] & 0xFFFFFFFFull);
    if ((gid & 127) == 0) {
        out_idx_f[row] = (float)idx;
        atomicAdd(&counts[idx], 1);
    }
    float4 e  = *(const float4*)&emb[(size_t)idx * DIMS + c4];
    float4 zv = *(const float4*)&z[(size_t)row * DIMS + c4];
    *(float4*)&outq[(size_t)row * DIMS + c4] = e;
    float dx = e.x - zv.x, dy = e.y - zv.y, dz = e.z - zv.z, dw = e.w - zv.w;
    float s = dx * dx + dy * dy + dz * dz + dw * dw;
    #pragma unroll
    for (int off = 32; off; off >>= 1) s += __shfl_down(s, off);
    __shared__ float wsum[4];
    if ((threadIdx.x & 63) == 0) wsum[threadIdx.x >> 6] = s;
    __syncthreads();
    if (threadIdx.x == 0)
        bsums[blockIdx.x] = wsum[0] + wsum[1] + wsum[2] + wsum[3];
}

// ---------------------------------------------------------------------------
// K5: finalize scalars: vq_loss and perplexity
// ---------------------------------------------------------------------------
__global__ __launch_bounds__(256)
void finalize_kernel(const int* __restrict__ counts, const float* __restrict__ bsums,
                     float* __restrict__ out_scalars)
{
    int t = threadIdx.x;
    double ls = 0.0, ps = 0.0;
    for (int i = t; i < 8192; i += 256) {
        ls += (double)bsums[i];
        double avg = (double)counts[i] * (1.0 / 16384.0);
        ps += avg * log(avg + 1e-10);
    }
    #pragma unroll
    for (int off = 32; off; off >>= 1) {
        ls += __shfl_down(ls, off);
        ps += __shfl_down(ps, off);
    }
    __shared__ double l4[4], p4[4];
    if ((t & 63) == 0) { l4[t >> 6] = ls; p4[t >> 6] = ps; }
    __syncthreads();
    if (t == 0) {
        double L = l4[0] + l4[1] + l4[2] + l4[3];
        double P = p4[0] + p4[1] + p4[2] + p4[3];
        out_scalars[0] = (float)(1.25 * L / 8388608.0);
        out_scalars[1] = (float)exp(-P);
    }
}

// ---------------------------------------------------------------------------
// ws layout (bytes):
//   rowkey u64[16384] @ 0       (131072)  (init by collect)
//   counts int[8192]  @ 131072  (32768)   (zeroed by collect)
//   ncand  int        @ 163840  (4)       (zeroed by prep)
//   bsums  f32[8192]  @ 164096  (32768)
//   esf    f32[8192]  @ 196864  (32768)
//   cand   u32[CAP]   @ 229632  (1048576)
// d_out scratch reuse (consumed before gather overwrites):
//   zh16 @ 0 (16MB) | eh16 @ 16777216 (8MB) | tab @ 25165824 (8MB)
// d_out final (floats): quantized[8388608] | vq_loss | perplexity | idx[16384]
// ---------------------------------------------------------------------------
extern "C" void kernel_launch(void* const* d_in, const int* in_sizes, int n_in,
                              void* d_out, int out_size, void* d_ws, size_t ws_size,
                              hipStream_t stream)
{
    const float* z   = (const float*)d_in[0];
    const float* emb = (const float*)d_in[1];

    float* out         = (float*)d_out;
    float* outq        = out;
    float* out_scalars = out + 8388608;
    float* out_idx     = out + 8388610;

    char* ob = (char*)d_out;
    _Float16* zh16 = (_Float16*)(ob + 0);
    _Float16* eh16 = (_Float16*)(ob + 16777216);
    unsigned long long* tab = (unsigned long long*)(ob + 25165824);

    char* ws = (char*)d_ws;
    unsigned long long* rowkey = (unsigned long long*)(ws + 0);
    int*      counts = (int*)     (ws + 131072);
    int*      ncand  = (int*)     (ws + 163840);
    float*    bsums  = (float*)   (ws + 164096);
    float*    esf    = (float*)   (ws + 196864);
    unsigned* cand   = (unsigned*)(ws + 229632);

    prep_kernel<<<3584, 256, 0, stream>>>(z, emb, zh16, eh16, esf, ncand);
    screen_kernel<<<dim3(64, 32), 256, 0, stream>>>((const char*)zh16,
                                                    (const char*)eh16, esf, tab);
    collect_kernel<<<4096, 256, 0, stream>>>(tab, cand, ncand, rowkey, counts);
    rescore_kernel<<<1024, 256, 0, stream>>>(z, emb, esf, cand, ncand, rowkey);
    gather_loss_kernel<<<8192, 256, 0, stream>>>(z, emb, rowkey, outq, out_idx,
                                                 counts, bsums);
    finalize_kernel<<<1, 256, 0, stream>>>(counts, bsums, out_scalars);
}

// Round 8
// 475.885 us; speedup vs baseline: 1.0558x; 1.0558x over previous
//
#include <hip/hip_runtime.h>
#include <math.h>

typedef _Float16 half8 __attribute__((ext_vector_type(8)));
typedef float    f32x4 __attribute__((ext_vector_type(4)));

#define NROWS 16384
#define DIMS  512
#define KC    8192
#define DELTA 0.5f
#define CAP   262144

// sortable-key helpers: smaller float -> smaller unsigned
__device__ inline unsigned fkey(float v) {
    unsigned u = __float_as_uint(v);
    return (u & 0x80000000u) ? ~u : (u | 0x80000000u);
}
__device__ inline float unfkey(unsigned u) {
    return (u & 0x80000000u) ? __uint_as_float(u & 0x7FFFFFFFu)
                             : __uint_as_float(~u);
}
__device__ inline unsigned long long shflxor_u64(unsigned long long v, int m) {
    int lo = __shfl_xor((int)(unsigned)(v & 0xffffffffull), m, 64);
    int hi = __shfl_xor((int)(unsigned)(v >> 32), m, 64);
    return ((unsigned long long)(unsigned)hi << 32) | (unsigned)lo;
}

// ---------------------------------------------------------------------------
// K0: fused prep. blocks [0,1024): cvt z panels; [1024,1536): cvt emb panels;
// [1536,3584): emb row sum-of-squares (fp64 accum); block 0 zeroes ncand.
// Packed layout (halfs): p*131072 + s*8192 + c*8, chunk c = f*64 + lg*16 + rr
// (p = 256-row panel, s = K-step of 32, f = 16-row fragment, lg = k-group,
// rr = row-in-fragment). 1KB fragment chunk read at +lane*16 is lane-linear.
// ---------------------------------------------------------------------------
__global__ __launch_bounds__(256)
void prep_kernel(const float* __restrict__ z, const float* __restrict__ emb,
                 _Float16* __restrict__ zh16, _Float16* __restrict__ eh16,
                 float* __restrict__ esf, int* __restrict__ ncand)
{
    int b = blockIdx.x, t = threadIdx.x;
    if (b == 0 && t == 0) *ncand = 0;
    if (b < 1536) {
        const float* src;
        _Float16* dst;
        int pb;
        if (b < 1024) { src = z;   dst = zh16; pb = b; }
        else          { src = emb; dst = eh16; pb = b - 1024; }
        int p = pb >> 4, s = pb & 15;
        _Float16* dbase = dst + (size_t)p * 131072 + s * 8192;
        #pragma unroll
        for (int q = 0; q < 4; ++q) {
            int c = q * 256 + t;
            int f = c >> 6, lg = (c >> 4) & 3, rr = c & 15;
            int row = p * 256 + f * 16 + rr;
            const float* sp = src + (size_t)row * DIMS + s * 32 + lg * 8;
            float4 v0 = *(const float4*)(sp + 0);
            float4 v1 = *(const float4*)(sp + 4);
            half8 h;
            h[0] = (_Float16)v0.x; h[1] = (_Float16)v0.y;
            h[2] = (_Float16)v0.z; h[3] = (_Float16)v0.w;
            h[4] = (_Float16)v1.x; h[5] = (_Float16)v1.y;
            h[6] = (_Float16)v1.z; h[7] = (_Float16)v1.w;
            *(half8*)(dbase + c * 8) = h;
        }
    } else {
        int b2 = b - 1536;
        int w = b2 * 4 + (t >> 6);
        int lane = t & 63;
        const float* r = emb + (size_t)w * DIMS;
        float4 v0 = *(const float4*)(r + lane * 4);
        float4 v1 = *(const float4*)(r + 256 + lane * 4);
        double s = (double)v0.x * v0.x + (double)v0.y * v0.y +
                   (double)v0.z * v0.z + (double)v0.w * v0.w +
                   (double)v1.x * v1.x + (double)v1.y * v1.y +
                   (double)v1.z * v1.z + (double)v1.w * v1.w;
        #pragma unroll
        for (int off = 32; off; off >>= 1) s += __shfl_down(s, off);
        if (lane == 0) esf[w] = (float)s;
    }
}

// ---------------------------------------------------------------------------
// K1: fp16 screen GEMM + per-(row, 128-col-block) packed top-2 entry.
// R8 structure (residency-first): 128x128 block, 4 waves (2Mx2N), wave tile
// 64x64 (i4 x j4, acc 64 AGPR + ~60 VGPR -> 3-4 waves/SIMD -> 3-4 BLOCKS
// co-resident per CU; inter-block overlap covers the barrier drain, m114).
// LDS: 2 x 16KB double buffer. Simple m97-style loop: stage-next via
// global_load_lds, ds_read frags (lane-linear, conflict-free), 16 MFMA,
// __syncthreads.
// tab entry u64: [63:32] fkey(v1) | [31:25] col1 | [24:13] dv q10 (floor,
// clamp 4095) | [12:6] col2  (cols within the 128-col block).
// ---------------------------------------------------------------------------
__global__ __launch_bounds__(256, 3)
void screen_kernel(const char* __restrict__ zh, const char* __restrict__ eh,
                   const float* __restrict__ esf,
                   unsigned long long* __restrict__ tab)
{
    __shared__ char smem[32768];   // 2 x (A 8K | B 8K)

    const int t    = threadIdx.x;
    const int lane = t & 63;
    const int wave = t >> 6;
    const int lg   = lane >> 4;
    const int lr   = lane & 15;
    const int wm   = wave >> 1;      // 0..1 row half (64 rows)
    const int wn   = wave & 1;       // 0..1 col half (64 cols)
    const int by   = blockIdx.x;     // col block 0..63  (fast: B reuse in L2)
    const int bx   = blockIdx.y;     // row block 0..127

    const char* gA = zh + (size_t)(bx >> 1) * 262144 + (bx & 1) * 8192;
    const char* gB = eh + (size_t)(by >> 1) * 262144 + (by & 1) * 8192;

    f32x4 acc[4][4];
    #pragma unroll
    for (int i = 0; i < 4; ++i)
        #pragma unroll
        for (int j = 0; j < 4; ++j)
            acc[i][j] = (f32x4){0.f, 0.f, 0.f, 0.f};

    typedef const __attribute__((address_space(1))) unsigned int gq_t;
    typedef __attribute__((address_space(3))) unsigned int lq_t;
    // stage K-step s (A 8KB + B 8KB): 4 gloads/thread, dst wave-uniform
    #define STAGE(dstbuf, s)                                                  \
    {                                                                         \
        const char* gsA = gA + (size_t)(s) * 16384;                          \
        const char* gsB = gB + (size_t)(s) * 16384;                          \
        _Pragma("unroll")                                                     \
        for (int k = 0; k < 2; ++k) {                                        \
            int off = wave * 2048 + k * 1024;                                \
            __builtin_amdgcn_global_load_lds(                                 \
                (gq_t*)(gsA + off + lane * 16),                               \
                (lq_t*)((dstbuf) + off), 16, 0, 0);                           \
            __builtin_amdgcn_global_load_lds(                                 \
                (gq_t*)(gsB + off + lane * 16),                               \
                (lq_t*)((dstbuf) + 8192 + off), 16, 0, 0);                    \
        }                                                                     \
    }

    char* p0 = smem;
    char* p1 = smem + 16384;
    STAGE(p0, 0);
    __syncthreads();

    #pragma unroll 1
    for (int s = 0; s < 16; ++s) {
        char* cur = (s & 1) ? p1 : p0;
        char* nxt = (s & 1) ? p0 : p1;
        if (s < 15) STAGE(nxt, s + 1);

        const char* Ab = cur + wm * 4096 + lane * 16;
        const char* Bb = cur + 8192 + wn * 4096 + lane * 16;
        half8 af[4], bf[4];
        #pragma unroll
        for (int i = 0; i < 4; ++i) af[i] = *(const half8*)(Ab + i * 1024);
        #pragma unroll
        for (int j = 0; j < 4; ++j) bf[j] = *(const half8*)(Bb + j * 1024);

        #pragma unroll
        for (int i = 0; i < 4; ++i)
            #pragma unroll
            for (int j = 0; j < 4; ++j)
                acc[i][j] = __builtin_amdgcn_mfma_f32_16x16x32_f16(
                    af[i], bf[j], acc[i][j], 0, 0, 0);

        __syncthreads();
    }

    // ---- epilogue: per-row top-2 within this block's 128 cols ----
    unsigned long long* mb = (unsigned long long*)smem;  // [128][2][2] = 4KB
    float es_j[4];
    #pragma unroll
    for (int j = 0; j < 4; ++j)
        es_j[j] = esf[by * 128 + wn * 64 + j * 16 + lr];

    #pragma unroll
    for (int i = 0; i < 4; ++i) {
        #pragma unroll
        for (int r = 0; r < 4; ++r) {
            unsigned long long k1 = ~0ull, k2 = ~0ull;
            #pragma unroll
            for (int j = 0; j < 4; ++j) {
                float v = fmaf(-2.f, acc[i][j][r], es_j[j]);
                int col = wn * 64 + j * 16 + lr;   // col within 128-block
                unsigned long long k =
                    ((unsigned long long)fkey(v) << 32) | (unsigned)col;
                if (k < k1) { k2 = k1; k1 = k; }
                else if (k < k2) { k2 = k; }
            }
            #pragma unroll
            for (int m = 1; m <= 8; m <<= 1) {
                unsigned long long o1 = shflxor_u64(k1, m);
                unsigned long long o2 = shflxor_u64(k2, m);
                unsigned long long n1 = k1 < o1 ? k1 : o1;
                unsigned long long hi = k1 < o1 ? o1 : k1;
                unsigned long long l2 = k2 < o2 ? k2 : o2;
                k1 = n1;
                k2 = hi < l2 ? hi : l2;
            }
            if (lr == 0) {
                int row = wm * 64 + i * 16 + lg * 4 + r;
                mb[(row * 2 + wn) * 2 + 0] = k1;
                mb[(row * 2 + wn) * 2 + 1] = k2;
            }
        }
    }
    __syncthreads();

    if (t < 128) {
        unsigned long long a1 = mb[(t * 2 + 0) * 2 + 0];
        unsigned long long a2 = mb[(t * 2 + 0) * 2 + 1];
        unsigned long long b1 = mb[(t * 2 + 1) * 2 + 0];
        unsigned long long b2 = mb[(t * 2 + 1) * 2 + 1];
        unsigned long long k1 = a1 < b1 ? a1 : b1;
        unsigned long long hi = a1 < b1 ? b1 : a1;
        unsigned long long lo2 = a1 < b1 ? a2 : b2;
        unsigned long long k2 = hi < lo2 ? hi : lo2;
        float v1 = unfkey((unsigned)(k1 >> 32));
        float v2 = unfkey((unsigned)(k2 >> 32));
        float dv = v2 - v1;
        int dvq = (int)(dv * 1024.0f);
        dvq = dvq < 0 ? 0 : (dvq > 4095 ? 4095 : dvq);
        unsigned long long entry = (k1 & 0xFFFFFFFF00000000ull)
                                 | ((k1 & 127ull) << 25)
                                 | ((unsigned long long)dvq << 13)
                                 | ((k2 & 127ull) << 6);
        tab[((size_t)(bx * 128 + t)) * 64 + by] = entry;
    }
}

// ---------------------------------------------------------------------------
// K2: collect candidates within DELTA of each row's approx min.
// One wave per row; lane = 128-col block. Unpacks the packed top-2 entry
// (dv floor-quantized -> conservative). Also inits rowkey + zeroes counts.
// ---------------------------------------------------------------------------
__global__ __launch_bounds__(256)
void collect_kernel(const unsigned long long* __restrict__ tab,
                    unsigned* __restrict__ cand, int* __restrict__ ncand,
                    unsigned long long* __restrict__ rowkey,
                    int* __restrict__ counts)
{
    int t = threadIdx.x, lane = t & 63;
    if (blockIdx.x < 32) counts[blockIdx.x * 256 + t] = 0;
    int row = blockIdx.x * 4 + (t >> 6);
    unsigned long long e = tab[(size_t)row * 64 + lane];
    unsigned fk1 = (unsigned)(e >> 32);
    unsigned m = fk1;
    #pragma unroll
    for (int mask = 1; mask <= 32; mask <<= 1) {
        unsigned o = (unsigned)__shfl_xor((int)m, mask, 64);
        m = o < m ? o : m;
    }
    if (lane == 0) rowkey[row] = ~0ull;
    float thr = unfkey(m) + DELTA;
    float v1 = unfkey(fk1);
    float v2 = v1 + (float)((e >> 13) & 4095u) * (1.0f / 1024.0f);
    int n1 = v1 <= thr ? 1 : 0;
    int n2 = v2 <= thr ? 1 : 0;
    if (n1 + n2) {
        int pos = atomicAdd(ncand, n1 + n2);
        unsigned base = (unsigned)row << 13 | (unsigned)(lane << 7);
        if (n1 && pos < CAP)
            cand[pos] = base | (unsigned)((e >> 25) & 127u);
        if (n2 && pos + n1 < CAP)
            cand[pos + n1] = base | (unsigned)((e >> 6) & 127u);
    }
}

// ---------------------------------------------------------------------------
// K3: exact fp32 rescore of candidates -> atomicMin final row keys.
// ---------------------------------------------------------------------------
__global__ __launch_bounds__(256)
void rescore_kernel(const float* __restrict__ z, const float* __restrict__ emb,
                    const float* __restrict__ esf,
                    const unsigned* __restrict__ cand,
                    const int* __restrict__ ncand,
                    unsigned long long* __restrict__ rowkey)
{
    int n = *ncand; if (n > CAP) n = CAP;
    int wid = blockIdx.x * 4 + (threadIdx.x >> 6);
    int lane = threadIdx.x & 63;
    for (int c = wid; c < n; c += 4096) {
        unsigned pc = cand[c];
        int row = pc >> 13, col = pc & 8191;
        const float4* zr = (const float4*)(z + (size_t)row * DIMS + lane * 8);
        const float4* er = (const float4*)(emb + (size_t)col * DIMS + lane * 8);
        float4 a0 = zr[0], a1 = zr[1], b0 = er[0], b1 = er[1];
        float s = a0.x * b0.x;
        s = fmaf(a0.y, b0.y, s); s = fmaf(a0.z, b0.z, s);
        s = fmaf(a0.w, b0.w, s); s = fmaf(a1.x, b1.x, s);
        s = fmaf(a1.y, b1.y, s); s = fmaf(a1.z, b1.z, s);
        s = fmaf(a1.w, b1.w, s);
        #pragma unroll
        for (int mask = 32; mask; mask >>= 1) s += __shfl_xor(s, mask);
        if (lane == 0) {
            float v = fmaf(-2.f, s, esf[col]);
            unsigned long long key =
                ((unsigned long long)fkey(v) << 32) | (unsigned)col;
            atomicMin(rowkey + row, key);
        }
    }
}

// ---------------------------------------------------------------------------
// K4: gather + loss partials + index output + histogram.
// ---------------------------------------------------------------------------
__global__ __launch_bounds__(256)
void gather_loss_kernel(const float* __restrict__ z, const float* __restrict__ emb,
                        const unsigned long long* __restrict__ rowkey,
                        float* __restrict__ outq, float* __restrict__ out_idx_f,
                        int* __restrict__ counts, float* __restrict__ bsums)
{
    int gid = blockIdx.x * 256 + threadIdx.x;
    int row = gid >> 7;
    int c4  = (gid & 127) << 2;
    int idx = (int)(rowkey[row] & 0xFFFFFFFFull);
    if ((gid & 127) == 0) {
        out_idx_f[row] = (float)idx;
        atomicAdd(&counts[idx], 1);
    }
    float4 e  = *(const float4*)&emb[(size_t)idx * DIMS + c4];
    float4 zv = *(const float4*)&z[(size_t)row * DIMS + c4];
    *(float4*)&outq[(size_t)row * DIMS + c4] = e;
    float dx = e.x - zv.x, dy = e.y - zv.y, dz = e.z - zv.z, dw = e.w - zv.w;
    float s = dx * dx + dy * dy + dz * dz + dw * dw;
    #pragma unroll
    for (int off = 32; off; off >>= 1) s += __shfl_down(s, off);
    __shared__ float wsum[4];
    if ((threadIdx.x & 63) == 0) wsum[threadIdx.x >> 6] = s;
    __syncthreads();
    if (threadIdx.x == 0)
        bsums[blockIdx.x] = wsum[0] + wsum[1] + wsum[2] + wsum[3];
}

// ---------------------------------------------------------------------------
// K5: finalize scalars: vq_loss and perplexity
// ---------------------------------------------------------------------------
__global__ __launch_bounds__(256)
void finalize_kernel(const int* __restrict__ counts, const float* __restrict__ bsums,
                     float* __restrict__ out_scalars)
{
    int t = threadIdx.x;
    double ls = 0.0, ps = 0.0;
    for (int i = t; i < 8192; i += 256) {
        ls += (double)bsums[i];
        double avg = (double)counts[i] * (1.0 / 16384.0);
        ps += avg * log(avg + 1e-10);
    }
    #pragma unroll
    for (int off = 32; off; off >>= 1) {
        ls += __shfl_down(ls, off);
        ps += __shfl_down(ps, off);
    }
    __shared__ double l4[4], p4[4];
    if ((t & 63) == 0) { l4[t >> 6] = ls; p4[t >> 6] = ps; }
    __syncthreads();
    if (t == 0) {
        double L = l4[0] + l4[1] + l4[2] + l4[3];
        double P = p4[0] + p4[1] + p4[2] + p4[3];
        out_scalars[0] = (float)(1.25 * L / 8388608.0);
        out_scalars[1] = (float)exp(-P);
    }
}

// ---------------------------------------------------------------------------
// ws layout (bytes):
//   rowkey u64[16384] @ 0       (131072)  (init by collect)
//   counts int[8192]  @ 131072  (32768)   (zeroed by collect)
//   ncand  int        @ 163840  (4)       (zeroed by prep)
//   bsums  f32[8192]  @ 164096  (32768)
//   esf    f32[8192]  @ 196864  (32768)
//   cand   u32[CAP]   @ 229632  (1048576)
// d_out scratch reuse (consumed before gather overwrites):
//   zh16 @ 0 (16MB) | eh16 @ 16777216 (8MB) | tab @ 25165824 (8MB)
// d_out final (floats): quantized[8388608] | vq_loss | perplexity | idx[16384]
// ---------------------------------------------------------------------------
extern "C" void kernel_launch(void* const* d_in, const int* in_sizes, int n_in,
                              void* d_out, int out_size, void* d_ws, size_t ws_size,
                              hipStream_t stream)
{
    const float* z   = (const float*)d_in[0];
    const float* emb = (const float*)d_in[1];

    float* out         = (float*)d_out;
    float* outq        = out;
    float* out_scalars = out + 8388608;
    float* out_idx     = out + 8388610;

    char* ob = (char*)d_out;
    _Float16* zh16 = (_Float16*)(ob + 0);
    _Float16* eh16 = (_Float16*)(ob + 16777216);
    unsigned long long* tab = (unsigned long long*)(ob + 25165824);

    char* ws = (char*)d_ws;
    unsigned long long* rowkey = (unsigned long long*)(ws + 0);
    int*      counts = (int*)     (ws + 131072);
    int*      ncand  = (int*)     (ws + 163840);
    float*    bsums  = (float*)   (ws + 164096);
    float*    esf    = (float*)   (ws + 196864);
    unsigned* cand   = (unsigned*)(ws + 229632);

    prep_kernel<<<3584, 256, 0, stream>>>(z, emb, zh16, eh16, esf, ncand);
    screen_kernel<<<dim3(64, 128), 256, 0, stream>>>((const char*)zh16,
                                                     (const char*)eh16, esf, tab);
    collect_kernel<<<4096, 256, 0, stream>>>(tab, cand, ncand, rowkey, counts);
    rescore_kernel<<<1024, 256, 0, stream>>>(z, emb, esf, cand, ncand, rowkey);
    gather_loss_kernel<<<8192, 256, 0, stream>>>(z, emb, rowkey, outq, out_idx,
                                                 counts, bsums);
    finalize_kernel<<<1, 256, 0, stream>>>(counts, bsums, out_scalars);
}

// Round 9
// 389.672 us; speedup vs baseline: 1.2894x; 1.2212x over previous
//
#include <hip/hip_runtime.h>
#include <math.h>

typedef _Float16 half8 __attribute__((ext_vector_type(8)));
typedef float    f32x4 __attribute__((ext_vector_type(4)));

#define NROWS 16384
#define DIMS  512
#define KC    8192
#define DELTA 0.5f
#define CAP   262144

__device__ inline unsigned fkey(float v) {
    unsigned u = __float_as_uint(v);
    return (u & 0x80000000u) ? ~u : (u | 0x80000000u);
}
__device__ inline float unfkey(unsigned u) {
    return (u & 0x80000000u) ? __uint_as_float(u & 0x7FFFFFFFu)
                             : __uint_as_float(~u);
}
__device__ inline unsigned umin_(unsigned a, unsigned b) { return a < b ? a : b; }
__device__ inline unsigned umax_(unsigned a, unsigned b) { return a > b ? a : b; }

// ---------------------------------------------------------------------------
// K0: fused prep. blocks [0,1024): cvt z panels; [1024,1536): cvt emb panels;
// [1536,3584): emb row sum-of-squares (fp64 accum); block 0 zeroes ncand.
// Packed layout (halfs): p*131072 + s*8192 + c*8, chunk c = f*64 + lg*16 + rr
// (p = 256-row panel, s = K-step of 32, f = 16-row fragment, lg = k-group,
// rr = row-in-fragment). 1KB fragment chunk read at +lane*16 is lane-linear.
// ---------------------------------------------------------------------------
__global__ __launch_bounds__(256)
void prep_kernel(const float* __restrict__ z, const float* __restrict__ emb,
                 _Float16* __restrict__ zh16, _Float16* __restrict__ eh16,
                 float* __restrict__ esf, int* __restrict__ ncand)
{
    int b = blockIdx.x, t = threadIdx.x;
    if (b == 0 && t == 0) *ncand = 0;
    if (b < 1536) {
        const float* src;
        _Float16* dst;
        int pb;
        if (b < 1024) { src = z;   dst = zh16; pb = b; }
        else          { src = emb; dst = eh16; pb = b - 1024; }
        int p = pb >> 4, s = pb & 15;
        _Float16* dbase = dst + (size_t)p * 131072 + s * 8192;
        #pragma unroll
        for (int q = 0; q < 4; ++q) {
            int c = q * 256 + t;
            int f = c >> 6, lg = (c >> 4) & 3, rr = c & 15;
            int row = p * 256 + f * 16 + rr;
            const float* sp = src + (size_t)row * DIMS + s * 32 + lg * 8;
            float4 v0 = *(const float4*)(sp + 0);
            float4 v1 = *(const float4*)(sp + 4);
            half8 h;
            h[0] = (_Float16)v0.x; h[1] = (_Float16)v0.y;
            h[2] = (_Float16)v0.z; h[3] = (_Float16)v0.w;
            h[4] = (_Float16)v1.x; h[5] = (_Float16)v1.y;
            h[6] = (_Float16)v1.z; h[7] = (_Float16)v1.w;
            *(half8*)(dbase + c * 8) = h;
        }
    } else {
        int b2 = b - 1536;
        int w = b2 * 4 + (t >> 6);
        int lane = t & 63;
        const float* r = emb + (size_t)w * DIMS;
        float4 v0 = *(const float4*)(r + lane * 4);
        float4 v1 = *(const float4*)(r + 256 + lane * 4);
        double s = (double)v0.x * v0.x + (double)v0.y * v0.y +
                   (double)v0.z * v0.z + (double)v0.w * v0.w +
                   (double)v1.x * v1.x + (double)v1.y * v1.y +
                   (double)v1.z * v1.z + (double)v1.w * v1.w;
        #pragma unroll
        for (int off = 32; off; off >>= 1) s += __shfl_down(s, off);
        if (lane == 0) esf[w] = (float)s;
    }
}

// ---------------------------------------------------------------------------
// K1: fp16 screen GEMM + per-(row, 128-col-block) top-2 (truncated-key).
// R9: 256x128 block, 4 waves (2Mx2N), wave tile 128x64 (i8 x j4):
// 12 ds_read_b128 (144 cyc LDS) vs 32 MFMA (155 cyc) per wave-step ->
// MFMA-bound at 2 waves/SIMD. acc = 128 AGPR, ~80 VGPR -> 2 blocks/CU
// co-resident; m97-style dbuf + __syncthreads (inter-block overlap covers
// the drain, m114). Fragment reads lane-linear: conflict-free.
// Epilogue: truncated u32 keys (fkey & ~127 | col7): per-thread top-2-of-4
// via 7 v_min/max_u32, padded LDS table, per-row sequential merge.
// tab entry u64 = k1<<32 | k2 (two truncated keys, cols local to 128-block).
// Grid: x = col-block (64 consecutive blocks share one A-panel -> L2 hot;
// eh16 8MB fully L2-resident).
// ---------------------------------------------------------------------------
__global__ __launch_bounds__(256, 2)
void screen_kernel(const char* __restrict__ zh, const char* __restrict__ eh,
                   const float* __restrict__ esf,
                   unsigned long long* __restrict__ tab)
{
    __shared__ char smem[67584];   // dbuf 2x24KB = 48KB; epilogue table 66KB

    const int t    = threadIdx.x;
    const int lane = t & 63;
    const int wave = t >> 6;
    const int lg   = lane >> 4;
    const int lr   = lane & 15;
    const int wm   = wave >> 1;      // 0..1 row half (128 rows)
    const int wn   = wave & 1;       // 0..1 col half (64 cols)
    const int by   = blockIdx.x;     // col block 0..63 (fast dim)
    const int bx   = blockIdx.y;     // row block 0..63

    const char* gA = zh + (size_t)bx * 262144;
    const char* gB = eh + (size_t)(by >> 1) * 262144 + (by & 1) * 8192;

    f32x4 acc[8][4];
    #pragma unroll
    for (int i = 0; i < 8; ++i)
        #pragma unroll
        for (int j = 0; j < 4; ++j)
            acc[i][j] = (f32x4){0.f, 0.f, 0.f, 0.f};

    typedef const __attribute__((address_space(1))) unsigned int gq_t;
    typedef __attribute__((address_space(3))) unsigned int lq_t;
    // stage K-step s: A 16KB (4 rounds) + B 8KB (2 rounds); 6 gloads/thread
    #define STAGE(dstbuf, s)                                                  \
    {                                                                         \
        const char* gsA = gA + (size_t)(s) * 16384;                          \
        const char* gsB = gB + (size_t)(s) * 16384;                          \
        _Pragma("unroll")                                                     \
        for (int k = 0; k < 4; ++k) {                                        \
            int off = k * 4096 + wave * 1024;                                \
            __builtin_amdgcn_global_load_lds(                                 \
                (gq_t*)(gsA + off + lane * 16),                               \
                (lq_t*)((dstbuf) + off), 16, 0, 0);                           \
        }                                                                     \
        _Pragma("unroll")                                                     \
        for (int k = 0; k < 2; ++k) {                                        \
            int off = k * 4096 + wave * 1024;                                \
            __builtin_amdgcn_global_load_lds(                                 \
                (gq_t*)(gsB + off + lane * 16),                               \
                (lq_t*)((dstbuf) + 16384 + off), 16, 0, 0);                   \
        }                                                                     \
    }
    #define COMPUTE(buf)                                                      \
    {                                                                         \
        const char* Ab = (buf) + (wm * 8) * 1024 + lane * 16;                 \
        const char* Bb = (buf) + 16384 + (wn * 4) * 1024 + lane * 16;         \
        half8 af[8], bf[4];                                                   \
        _Pragma("unroll")                                                     \
        for (int i = 0; i < 8; ++i) af[i] = *(const half8*)(Ab + i * 1024);   \
        _Pragma("unroll")                                                     \
        for (int j = 0; j < 4; ++j) bf[j] = *(const half8*)(Bb + j * 1024);   \
        _Pragma("unroll")                                                     \
        for (int i = 0; i < 8; ++i)                                           \
            _Pragma("unroll")                                                 \
            for (int j = 0; j < 4; ++j)                                       \
                acc[i][j] = __builtin_amdgcn_mfma_f32_16x16x32_f16(           \
                    af[i], bf[j], acc[i][j], 0, 0, 0);                        \
    }

    char* p0 = smem;
    char* p1 = smem + 24576;
    STAGE(p0, 0);
    __syncthreads();

    #pragma unroll 1
    for (int s = 0; s < 16; s += 2) {
        STAGE(p1, s + 1);
        COMPUTE(p0);
        __syncthreads();
        if (s + 2 < 16) STAGE(p0, s + 2);
        COMPUTE(p1);
        __syncthreads();
    }

    // ---- epilogue pass 1: per-thread top-2-of-4, truncated u32 keys ----
    unsigned long long* mb = (unsigned long long*)smem;  // stride 33/row
    float es_j[4];
    #pragma unroll
    for (int j = 0; j < 4; ++j)
        es_j[j] = esf[by * 128 + wn * 64 + j * 16 + lr];

    #pragma unroll
    for (int i = 0; i < 8; ++i) {
        #pragma unroll
        for (int r = 0; r < 4; ++r) {
            unsigned k[4];
            #pragma unroll
            for (int j = 0; j < 4; ++j) {
                float v = fmaf(-2.f, acc[i][j][r], es_j[j]);
                k[j] = (fkey(v) & 0xFFFFFF80u)
                     | (unsigned)(wn * 64 + j * 16 + lr);
            }
            unsigned lo1 = umin_(k[0], k[1]), hi1 = umax_(k[0], k[1]);
            unsigned lo2 = umin_(k[2], k[3]), hi2 = umax_(k[2], k[3]);
            unsigned k1 = umin_(lo1, lo2);
            unsigned k2 = umin_(umax_(lo1, lo2), umin_(hi1, hi2));
            int row = wm * 128 + i * 16 + lg * 4 + r;
            mb[row * 33 + wn * 16 + lr] =
                ((unsigned long long)k1 << 32) | k2;
        }
    }
    __syncthreads();

    // ---- epilogue pass 2: one row per thread, merge 32 sorted pairs ----
    {
        unsigned b1 = 0xFFFFFFFFu, b2 = 0xFFFFFFFFu;
        #pragma unroll 4
        for (int q = 0; q < 32; ++q) {
            unsigned long long e = mb[t * 33 + q];
            unsigned e1 = (unsigned)(e >> 32), e2 = (unsigned)e;
            unsigned nb1 = umin_(b1, e1);
            b2 = umin_(umax_(b1, e1), umin_(b2, e2));
            b1 = nb1;
        }
        tab[((size_t)(bx * 256 + t)) * 64 + by] =
            ((unsigned long long)b1 << 32) | b2;
    }
}

// ---------------------------------------------------------------------------
// K2: collect candidates within DELTA of each row's approx min.
// One wave per row; lane = 128-col block. Keys are truncated (floor) ->
// thresholds conservative. Also inits rowkey + zeroes counts.
// ---------------------------------------------------------------------------
__global__ __launch_bounds__(256)
void collect_kernel(const unsigned long long* __restrict__ tab,
                    unsigned* __restrict__ cand, int* __restrict__ ncand,
                    unsigned long long* __restrict__ rowkey,
                    int* __restrict__ counts)
{
    int t = threadIdx.x, lane = t & 63;
    if (blockIdx.x < 32) counts[blockIdx.x * 256 + t] = 0;
    int row = blockIdx.x * 4 + (t >> 6);
    unsigned long long e = tab[(size_t)row * 64 + lane];
    unsigned k1 = (unsigned)(e >> 32), k2 = (unsigned)e;
    unsigned m = k1;
    #pragma unroll
    for (int mask = 1; mask <= 32; mask <<= 1) {
        unsigned o = (unsigned)__shfl_xor((int)m, mask, 64);
        m = umin_(m, o);
    }
    if (lane == 0) rowkey[row] = ~0ull;
    float thr = unfkey(m & 0xFFFFFF80u) + DELTA;
    float v1 = unfkey(k1 & 0xFFFFFF80u);
    float v2 = unfkey(k2 & 0xFFFFFF80u);
    int n1 = v1 <= thr ? 1 : 0;
    int n2 = v2 <= thr ? 1 : 0;
    if (n1 + n2) {
        int pos = atomicAdd(ncand, n1 + n2);
        unsigned base = ((unsigned)row << 13) | ((unsigned)lane << 7);
        if (n1 && pos < CAP)
            cand[pos] = base | (k1 & 127u);
        if (n2 && pos + n1 < CAP)
            cand[pos + n1] = base | (k2 & 127u);
    }
}

// ---------------------------------------------------------------------------
// K3: exact fp32 rescore of candidates -> atomicMin final row keys.
// ---------------------------------------------------------------------------
__global__ __launch_bounds__(256)
void rescore_kernel(const float* __restrict__ z, const float* __restrict__ emb,
                    const float* __restrict__ esf,
                    const unsigned* __restrict__ cand,
                    const int* __restrict__ ncand,
                    unsigned long long* __restrict__ rowkey)
{
    int n = *ncand; if (n > CAP) n = CAP;
    int wid = blockIdx.x * 4 + (threadIdx.x >> 6);
    int lane = threadIdx.x & 63;
    for (int c = wid; c < n; c += 4096) {
        unsigned pc = cand[c];
        int row = pc >> 13, col = pc & 8191;
        const float4* zr = (const float4*)(z + (size_t)row * DIMS + lane * 8);
        const float4* er = (const float4*)(emb + (size_t)col * DIMS + lane * 8);
        float4 a0 = zr[0], a1 = zr[1], b0 = er[0], b1 = er[1];
        float s = a0.x * b0.x;
        s = fmaf(a0.y, b0.y, s); s = fmaf(a0.z, b0.z, s);
        s = fmaf(a0.w, b0.w, s); s = fmaf(a1.x, b1.x, s);
        s = fmaf(a1.y, b1.y, s); s = fmaf(a1.z, b1.z, s);
        s = fmaf(a1.w, b1.w, s);
        #pragma unroll
        for (int mask = 32; mask; mask >>= 1) s += __shfl_xor(s, mask);
        if (lane == 0) {
            float v = fmaf(-2.f, s, esf[col]);
            unsigned long long key =
                ((unsigned long long)fkey(v) << 32) | (unsigned)col;
            atomicMin(rowkey + row, key);
        }
    }
}

// ---------------------------------------------------------------------------
// K4: gather + loss partials + index output + histogram.
// ---------------------------------------------------------------------------
__global__ __launch_bounds__(256)
void gather_loss_kernel(const float* __restrict__ z, const float* __restrict__ emb,
                        const unsigned long long* __restrict__ rowkey,
                        float* __restrict__ outq, float* __restrict__ out_idx_f,
                        int* __restrict__ counts, float* __restrict__ bsums)
{
    int gid = blockIdx.x * 256 + threadIdx.x;
    int row = gid >> 7;
    int c4  = (gid & 127) << 2;
    int idx = (int)(rowkey[row] & 0xFFFFFFFFull);
    if ((gid & 127) == 0) {
        out_idx_f[row] = (float)idx;
        atomicAdd(&counts[idx], 1);
    }
    float4 e  = *(const float4*)&emb[(size_t)idx * DIMS + c4];
    float4 zv = *(const float4*)&z[(size_t)row * DIMS + c4];
    *(float4*)&outq[(size_t)row * DIMS + c4] = e;
    float dx = e.x - zv.x, dy = e.y - zv.y, dz = e.z - zv.z, dw = e.w - zv.w;
    float s = dx * dx + dy * dy + dz * dz + dw * dw;
    #pragma unroll
    for (int off = 32; off; off >>= 1) s += __shfl_down(s, off);
    __shared__ float wsum[4];
    if ((threadIdx.x & 63) == 0) wsum[threadIdx.x >> 6] = s;
    __syncthreads();
    if (threadIdx.x == 0)
        bsums[blockIdx.x] = wsum[0] + wsum[1] + wsum[2] + wsum[3];
}

// ---------------------------------------------------------------------------
// K5: finalize scalars: vq_loss and perplexity
// ---------------------------------------------------------------------------
__global__ __launch_bounds__(256)
void finalize_kernel(const int* __restrict__ counts, const float* __restrict__ bsums,
                     float* __restrict__ out_scalars)
{
    int t = threadIdx.x;
    double ls = 0.0, ps = 0.0;
    for (int i = t; i < 8192; i += 256) {
        ls += (double)bsums[i];
        double avg = (double)counts[i] * (1.0 / 16384.0);
        ps += avg * log(avg + 1e-10);
    }
    #pragma unroll
    for (int off = 32; off; off >>= 1) {
        ls += __shfl_down(ls, off);
        ps += __shfl_down(ps, off);
    }
    __shared__ double l4[4], p4[4];
    if ((t & 63) == 0) { l4[t >> 6] = ls; p4[t >> 6] = ps; }
    __syncthreads();
    if (t == 0) {
        double L = l4[0] + l4[1] + l4[2] + l4[3];
        double P = p4[0] + p4[1] + p4[2] + p4[3];
        out_scalars[0] = (float)(1.25 * L / 8388608.0);
        out_scalars[1] = (float)exp(-P);
    }
}

// ---------------------------------------------------------------------------
// ws layout (bytes):
//   rowkey u64[16384] @ 0       (131072)  (init by collect)
//   counts int[8192]  @ 131072  (32768)   (zeroed by collect)
//   ncand  int        @ 163840  (4)       (zeroed by prep)
//   bsums  f32[8192]  @ 164096  (32768)
//   esf    f32[8192]  @ 196864  (32768)
//   cand   u32[CAP]   @ 229632  (1048576)
// d_out scratch reuse (consumed before gather overwrites):
//   zh16 @ 0 (16MB) | eh16 @ 16777216 (8MB) | tab @ 25165824 (8MB)
// d_out final (floats): quantized[8388608] | vq_loss | perplexity | idx[16384]
// ---------------------------------------------------------------------------
extern "C" void kernel_launch(void* const* d_in, const int* in_sizes, int n_in,
                              void* d_out, int out_size, void* d_ws, size_t ws_size,
                              hipStream_t stream)
{
    const float* z   = (const float*)d_in[0];
    const float* emb = (const float*)d_in[1];

    float* out         = (float*)d_out;
    float* outq        = out;
    float* out_scalars = out + 8388608;
    float* out_idx     = out + 8388610;

    char* ob = (char*)d_out;
    _Float16* zh16 = (_Float16*)(ob + 0);
    _Float16* eh16 = (_Float16*)(ob + 16777216);
    unsigned long long* tab = (unsigned long long*)(ob + 25165824);

    char* ws = (char*)d_ws;
    unsigned long long* rowkey = (unsigned long long*)(ws + 0);
    int*      counts = (int*)     (ws + 131072);
    int*      ncand  = (int*)     (ws + 163840);
    float*    bsums  = (float*)   (ws + 164096);
    float*    esf    = (float*)   (ws + 196864);
    unsigned* cand   = (unsigned*)(ws + 229632);

    prep_kernel<<<3584, 256, 0, stream>>>(z, emb, zh16, eh16, esf, ncand);
    screen_kernel<<<dim3(64, 64), 256, 0, stream>>>((const char*)zh16,
                                                    (const char*)eh16, esf, tab);
    collect_kernel<<<4096, 256, 0, stream>>>(tab, cand, ncand, rowkey, counts);
    rescore_kernel<<<1024, 256, 0, stream>>>(z, emb, esf, cand, ncand, rowkey);
    gather_loss_kernel<<<8192, 256, 0, stream>>>(z, emb, rowkey, outq, out_idx,
                                                 counts, bsums);
    finalize_kernel<<<1, 256, 0, stream>>>(counts, bsums, out_scalars);
}

// Round 10
// 201.499 us; speedup vs baseline: 2.4936x; 1.9339x over previous
//
#include <hip/hip_runtime.h>
#include <math.h>

typedef _Float16 half8 __attribute__((ext_vector_type(8)));
typedef float    f32x4 __attribute__((ext_vector_type(4)));

#define NROWS 16384
#define DIMS  512
#define KC    8192
#define DELTA 0.5f

__device__ inline unsigned fkey(float v) {
    unsigned u = __float_as_uint(v);
    return (u & 0x80000000u) ? ~u : (u | 0x80000000u);
}
__device__ inline float unfkey(unsigned u) {
    return (u & 0x80000000u) ? __uint_as_float(u & 0x7FFFFFFFu)
                             : __uint_as_float(~u);
}
__device__ inline unsigned umin_(unsigned a, unsigned b) { return a < b ? a : b; }
__device__ inline unsigned umax_(unsigned a, unsigned b) { return a > b ? a : b; }

// ---------------------------------------------------------------------------
// K0: fused prep. blocks [0,1024): cvt z panels; [1024,1536): cvt emb panels;
// [1536,3584): emb row sum-of-squares (fp64 accum).
// Packed layout (halfs): p*131072 + s*8192 + c*8, chunk c = f*64 + lg*16 + rr
// (p = 256-row panel, s = K-step of 32, f = 16-row fragment, lg = k-group,
// rr = row-in-fragment). 1KB fragment chunk read at +lane*16 is lane-linear.
// ---------------------------------------------------------------------------
__global__ __launch_bounds__(256)
void prep_kernel(const float* __restrict__ z, const float* __restrict__ emb,
                 _Float16* __restrict__ zh16, _Float16* __restrict__ eh16,
                 float* __restrict__ esf)
{
    int b = blockIdx.x, t = threadIdx.x;
    if (b < 1536) {
        const float* src;
        _Float16* dst;
        int pb;
        if (b < 1024) { src = z;   dst = zh16; pb = b; }
        else          { src = emb; dst = eh16; pb = b - 1024; }
        int p = pb >> 4, s = pb & 15;
        _Float16* dbase = dst + (size_t)p * 131072 + s * 8192;
        #pragma unroll
        for (int q = 0; q < 4; ++q) {
            int c = q * 256 + t;
            int f = c >> 6, lg = (c >> 4) & 3, rr = c & 15;
            int row = p * 256 + f * 16 + rr;
            const float* sp = src + (size_t)row * DIMS + s * 32 + lg * 8;
            float4 v0 = *(const float4*)(sp + 0);
            float4 v1 = *(const float4*)(sp + 4);
            half8 h;
            h[0] = (_Float16)v0.x; h[1] = (_Float16)v0.y;
            h[2] = (_Float16)v0.z; h[3] = (_Float16)v0.w;
            h[4] = (_Float16)v1.x; h[5] = (_Float16)v1.y;
            h[6] = (_Float16)v1.z; h[7] = (_Float16)v1.w;
            *(half8*)(dbase + c * 8) = h;
        }
    } else {
        int b2 = b - 1536;
        int w = b2 * 4 + (t >> 6);
        int lane = t & 63;
        const float* r = emb + (size_t)w * DIMS;
        float4 v0 = *(const float4*)(r + lane * 4);
        float4 v1 = *(const float4*)(r + 256 + lane * 4);
        double s = (double)v0.x * v0.x + (double)v0.y * v0.y +
                   (double)v0.z * v0.z + (double)v0.w * v0.w +
                   (double)v1.x * v1.x + (double)v1.y * v1.y +
                   (double)v1.z * v1.z + (double)v1.w * v1.w;
        #pragma unroll
        for (int off = 32; off; off >>= 1) s += __shfl_down(s, off);
        if (lane == 0) esf[w] = (float)s;
    }
}

// ---------------------------------------------------------------------------
// K1: fp16 screen GEMM + per-(row, 128-col-block) top-2 (truncated-key).
// 256x128 block, 4 waves (2Mx2N), wave tile 128x64 (i8 x j4), dbuf 48KB,
// 2 blocks/CU co-resident (m114 overlap covers the sync drain).
// Fragment reads lane-linear: conflict-free.
// tab entry u64 = k1<<32 | k2 (truncated keys: fkey&~127 | col7, cols local
// to the 128-col block).
// ---------------------------------------------------------------------------
__global__ __launch_bounds__(256, 2)
void screen_kernel(const char* __restrict__ zh, const char* __restrict__ eh,
                   const float* __restrict__ esf,
                   unsigned long long* __restrict__ tab)
{
    __shared__ char smem[67584];   // dbuf 2x24KB; epilogue table 66KB

    const int t    = threadIdx.x;
    const int lane = t & 63;
    const int wave = t >> 6;
    const int lg   = lane >> 4;
    const int lr   = lane & 15;
    const int wm   = wave >> 1;      // 0..1 row half (128 rows)
    const int wn   = wave & 1;       // 0..1 col half (64 cols)
    const int by   = blockIdx.x;     // col block 0..63 (fast dim)
    const int bx   = blockIdx.y;     // row block 0..63

    const char* gA = zh + (size_t)bx * 262144;
    const char* gB = eh + (size_t)(by >> 1) * 262144 + (by & 1) * 8192;

    f32x4 acc[8][4];
    #pragma unroll
    for (int i = 0; i < 8; ++i)
        #pragma unroll
        for (int j = 0; j < 4; ++j)
            acc[i][j] = (f32x4){0.f, 0.f, 0.f, 0.f};

    typedef const __attribute__((address_space(1))) unsigned int gq_t;
    typedef __attribute__((address_space(3))) unsigned int lq_t;
    #define STAGE(dstbuf, s)                                                  \
    {                                                                         \
        const char* gsA = gA + (size_t)(s) * 16384;                          \
        const char* gsB = gB + (size_t)(s) * 16384;                          \
        _Pragma("unroll")                                                     \
        for (int k = 0; k < 4; ++k) {                                        \
            int off = k * 4096 + wave * 1024;                                \
            __builtin_amdgcn_global_load_lds(                                 \
                (gq_t*)(gsA + off + lane * 16),                               \
                (lq_t*)((dstbuf) + off), 16, 0, 0);                           \
        }                                                                     \
        _Pragma("unroll")                                                     \
        for (int k = 0; k < 2; ++k) {                                        \
            int off = k * 4096 + wave * 1024;                                \
            __builtin_amdgcn_global_load_lds(                                 \
                (gq_t*)(gsB + off + lane * 16),                               \
                (lq_t*)((dstbuf) + 16384 + off), 16, 0, 0);                   \
        }                                                                     \
    }
    #define COMPUTE(buf)                                                      \
    {                                                                         \
        const char* Ab = (buf) + (wm * 8) * 1024 + lane * 16;                 \
        const char* Bb = (buf) + 16384 + (wn * 4) * 1024 + lane * 16;         \
        half8 af[8], bf[4];                                                   \
        _Pragma("unroll")                                                     \
        for (int i = 0; i < 8; ++i) af[i] = *(const half8*)(Ab + i * 1024);   \
        _Pragma("unroll")                                                     \
        for (int j = 0; j < 4; ++j) bf[j] = *(const half8*)(Bb + j * 1024);   \
        _Pragma("unroll")                                                     \
        for (int i = 0; i < 8; ++i)                                           \
            _Pragma("unroll")                                                 \
            for (int j = 0; j < 4; ++j)                                       \
                acc[i][j] = __builtin_amdgcn_mfma_f32_16x16x32_f16(           \
                    af[i], bf[j], acc[i][j], 0, 0, 0);                        \
    }

    char* p0 = smem;
    char* p1 = smem + 24576;
    STAGE(p0, 0);
    __syncthreads();

    #pragma unroll 1
    for (int s = 0; s < 16; s += 2) {
        STAGE(p1, s + 1);
        COMPUTE(p0);
        __syncthreads();
        if (s + 2 < 16) STAGE(p0, s + 2);
        COMPUTE(p1);
        __syncthreads();
    }

    // ---- epilogue pass 1: per-thread top-2-of-4, truncated u32 keys ----
    unsigned long long* mb = (unsigned long long*)smem;  // stride 33/row
    float es_j[4];
    #pragma unroll
    for (int j = 0; j < 4; ++j)
        es_j[j] = esf[by * 128 + wn * 64 + j * 16 + lr];

    #pragma unroll
    for (int i = 0; i < 8; ++i) {
        #pragma unroll
        for (int r = 0; r < 4; ++r) {
            unsigned k[4];
            #pragma unroll
            for (int j = 0; j < 4; ++j) {
                float v = fmaf(-2.f, acc[i][j][r], es_j[j]);
                k[j] = (fkey(v) & 0xFFFFFF80u)
                     | (unsigned)(wn * 64 + j * 16 + lr);
            }
            unsigned lo1 = umin_(k[0], k[1]), hi1 = umax_(k[0], k[1]);
            unsigned lo2 = umin_(k[2], k[3]), hi2 = umax_(k[2], k[3]);
            unsigned k1 = umin_(lo1, lo2);
            unsigned k2 = umin_(umax_(lo1, lo2), umin_(hi1, hi2));
            int row = wm * 128 + i * 16 + lg * 4 + r;
            mb[row * 33 + wn * 16 + lr] =
                ((unsigned long long)k1 << 32) | k2;
        }
    }
    __syncthreads();

    // ---- epilogue pass 2: one row per thread, merge 32 sorted pairs ----
    {
        unsigned b1 = 0xFFFFFFFFu, b2 = 0xFFFFFFFFu;
        #pragma unroll 4
        for (int q = 0; q < 32; ++q) {
            unsigned long long e = mb[t * 33 + q];
            unsigned e1 = (unsigned)(e >> 32), e2 = (unsigned)e;
            unsigned nb1 = umin_(b1, e1);
            b2 = umin_(umax_(b1, e1), umin_(b2, e2));
            b1 = nb1;
        }
        tab[((size_t)(bx * 256 + t)) * 64 + by] =
            ((unsigned long long)b1 << 32) | b2;
    }
}

// ---------------------------------------------------------------------------
// K2: fused collect + exact rescore, ZERO global atomics.
// One wave per row: shuffle-min over 64 tab keys -> threshold; ballot the
// candidate lanes (wave-uniform masks); loop over set bits (~1 iter/row):
// broadcast col, all 64 lanes cooperatively fp32-dot z[row].emb[col]
// (identical op structure to the previous passing rescore), fold min-key;
// lane 0 plain-stores rowkey[row]. Every row's own argmin block passes the
// threshold, so rowkey is always written. Also zeroes counts.
// ---------------------------------------------------------------------------
__global__ __launch_bounds__(256)
void collect_rescore_kernel(const float* __restrict__ z,
                            const float* __restrict__ emb,
                            const float* __restrict__ esf,
                            const unsigned long long* __restrict__ tab,
                            unsigned long long* __restrict__ rowkey,
                            int* __restrict__ counts)
{
    int t = threadIdx.x, lane = t & 63;
    if (blockIdx.x < 32) counts[blockIdx.x * 256 + t] = 0;
    int row = blockIdx.x * 4 + (t >> 6);

    unsigned long long e = tab[(size_t)row * 64 + lane];
    unsigned k1 = (unsigned)(e >> 32), k2 = (unsigned)e;
    unsigned m = k1;
    #pragma unroll
    for (int mask = 1; mask <= 32; mask <<= 1) {
        unsigned o = (unsigned)__shfl_xor((int)m, mask, 64);
        m = umin_(m, o);
    }
    float thr = unfkey(m & 0xFFFFFF80u) + DELTA;
    bool c1 = unfkey(k1 & 0xFFFFFF80u) <= thr;
    bool c2 = unfkey(k2 & 0xFFFFFF80u) <= thr;
    unsigned long long m1 = __ballot(c1);
    unsigned long long m2 = __ballot(c2);

    const float4* zr = (const float4*)(z + (size_t)row * DIMS + lane * 8);
    float4 a0 = zr[0], a1 = zr[1];

    unsigned long long best = ~0ull;
    while (m1 | m2) {
        int src;
        unsigned kk;
        if (m1) {
            src = __ffsll((long long)m1) - 1;
            m1 &= m1 - 1;
            kk = (unsigned)__shfl((int)k1, src, 64);
        } else {
            src = __ffsll((long long)m2) - 1;
            m2 &= m2 - 1;
            kk = (unsigned)__shfl((int)k2, src, 64);
        }
        int col = src * 128 + (int)(kk & 127u);

        const float4* er = (const float4*)(emb + (size_t)col * DIMS + lane * 8);
        float4 b0 = er[0], b1v = er[1];
        float s = a0.x * b0.x;
        s = fmaf(a0.y, b0.y, s); s = fmaf(a0.z, b0.z, s);
        s = fmaf(a0.w, b0.w, s); s = fmaf(a1.x, b1v.x, s);
        s = fmaf(a1.y, b1v.y, s); s = fmaf(a1.z, b1v.z, s);
        s = fmaf(a1.w, b1v.w, s);
        #pragma unroll
        for (int mask = 32; mask; mask >>= 1) s += __shfl_xor(s, mask);
        float v = fmaf(-2.f, s, esf[col]);
        unsigned long long key =
            ((unsigned long long)fkey(v) << 32) | (unsigned)col;
        best = key < best ? key : best;
    }
    if (lane == 0) rowkey[row] = best;
}

// ---------------------------------------------------------------------------
// K3: gather + loss partials + index output + histogram.
// ---------------------------------------------------------------------------
__global__ __launch_bounds__(256)
void gather_loss_kernel(const float* __restrict__ z, const float* __restrict__ emb,
                        const unsigned long long* __restrict__ rowkey,
                        float* __restrict__ outq, float* __restrict__ out_idx_f,
                        int* __restrict__ counts, float* __restrict__ bsums)
{
    int gid = blockIdx.x * 256 + threadIdx.x;
    int row = gid >> 7;
    int c4  = (gid & 127) << 2;
    int idx = (int)(rowkey[row] & 0xFFFFFFFFull);
    if ((gid & 127) == 0) {
        out_idx_f[row] = (float)idx;
        atomicAdd(&counts[idx], 1);
    }
    float4 e  = *(const float4*)&emb[(size_t)idx * DIMS + c4];
    float4 zv = *(const float4*)&z[(size_t)row * DIMS + c4];
    *(float4*)&outq[(size_t)row * DIMS + c4] = e;
    float dx = e.x - zv.x, dy = e.y - zv.y, dz = e.z - zv.z, dw = e.w - zv.w;
    float s = dx * dx + dy * dy + dz * dz + dw * dw;
    #pragma unroll
    for (int off = 32; off; off >>= 1) s += __shfl_down(s, off);
    __shared__ float wsum[4];
    if ((threadIdx.x & 63) == 0) wsum[threadIdx.x >> 6] = s;
    __syncthreads();
    if (threadIdx.x == 0)
        bsums[blockIdx.x] = wsum[0] + wsum[1] + wsum[2] + wsum[3];
}

// ---------------------------------------------------------------------------
// K4: finalize scalars: vq_loss and perplexity
// ---------------------------------------------------------------------------
__global__ __launch_bounds__(256)
void finalize_kernel(const int* __restrict__ counts, const float* __restrict__ bsums,
                     float* __restrict__ out_scalars)
{
    int t = threadIdx.x;
    double ls = 0.0, ps = 0.0;
    for (int i = t; i < 8192; i += 256) {
        ls += (double)bsums[i];
        double avg = (double)counts[i] * (1.0 / 16384.0);
        ps += avg * log(avg + 1e-10);
    }
    #pragma unroll
    for (int off = 32; off; off >>= 1) {
        ls += __shfl_down(ls, off);
        ps += __shfl_down(ps, off);
    }
    __shared__ double l4[4], p4[4];
    if ((t & 63) == 0) { l4[t >> 6] = ls; p4[t >> 6] = ps; }
    __syncthreads();
    if (t == 0) {
        double L = l4[0] + l4[1] + l4[2] + l4[3];
        double P = p4[0] + p4[1] + p4[2] + p4[3];
        out_scalars[0] = (float)(1.25 * L / 8388608.0);
        out_scalars[1] = (float)exp(-P);
    }
}

// ---------------------------------------------------------------------------
// ws layout (bytes):
//   rowkey u64[16384] @ 0       (131072)  (written by collect_rescore)
//   counts int[8192]  @ 131072  (32768)   (zeroed by collect_rescore)
//   bsums  f32[8192]  @ 164096  (32768)
//   esf    f32[8192]  @ 196864  (32768)
// d_out scratch reuse (consumed before gather overwrites):
//   zh16 @ 0 (16MB) | eh16 @ 16777216 (8MB) | tab @ 25165824 (8MB)
// d_out final (floats): quantized[8388608] | vq_loss | perplexity | idx[16384]
// ---------------------------------------------------------------------------
extern "C" void kernel_launch(void* const* d_in, const int* in_sizes, int n_in,
                              void* d_out, int out_size, void* d_ws, size_t ws_size,
                              hipStream_t stream)
{
    const float* z   = (const float*)d_in[0];
    const float* emb = (const float*)d_in[1];

    float* out         = (float*)d_out;
    float* outq        = out;
    float* out_scalars = out + 8388608;
    float* out_idx     = out + 8388610;

    char* ob = (char*)d_out;
    _Float16* zh16 = (_Float16*)(ob + 0);
    _Float16* eh16 = (_Float16*)(ob + 16777216);
    unsigned long long* tab = (unsigned long long*)(ob + 25165824);

    char* ws = (char*)d_ws;
    unsigned long long* rowkey = (unsigned long long*)(ws + 0);
    int*   counts = (int*)  (ws + 131072);
    float* bsums  = (float*)(ws + 164096);
    float* esf    = (float*)(ws + 196864);

    prep_kernel<<<3584, 256, 0, stream>>>(z, emb, zh16, eh16, esf);
    screen_kernel<<<dim3(64, 64), 256, 0, stream>>>((const char*)zh16,
                                                    (const char*)eh16, esf, tab);
    collect_rescore_kernel<<<4096, 256, 0, stream>>>(z, emb, esf, tab,
                                                     rowkey, counts);
    gather_loss_kernel<<<8192, 256, 0, stream>>>(z, emb, rowkey, outq, out_idx,
                                                 counts, bsums);
    finalize_kernel<<<1, 256, 0, stream>>>(counts, bsums, out_scalars);
}